// Round 9
// baseline (606.136 us; speedup 1.0000x reference)
//
#include <hip/hip_runtime.h>
#include <stdint.h>

typedef __bf16 bf16x8 __attribute__((ext_vector_type(8)));
typedef float floatx4 __attribute__((ext_vector_type(4)));

__device__ __forceinline__ void gload_lds16(const void* g, void* l) {
    __builtin_amdgcn_global_load_lds((const __attribute__((address_space(1))) void*)g,
                                     (__attribute__((address_space(3))) void*)l, 16, 0, 0);
}

__device__ __forceinline__ uint16_t f2bf(float f) {
    uint32_t u = __float_as_uint(f);
    u += 0x7fff + ((u >> 16) & 1);   // RNE
    return (uint16_t)(u >> 16);
}
__device__ __forceinline__ uint32_t f2bf2(float lo, float hi) {
    return (uint32_t)f2bf(lo) | ((uint32_t)f2bf(hi) << 16);
}

// ---- flag sync (producers/consumers co-resident by construction) ----------
__device__ __forceinline__ void bump(int* p) {
    __syncthreads();                      // all waves' stores drained to L2
    if (threadIdx.x == 0)
        __hip_atomic_fetch_add(p, 1, __ATOMIC_RELEASE, __HIP_MEMORY_SCOPE_AGENT);
}
// relaxed spin (no per-iteration L2 invalidation), one acquire fence at the end
__device__ __forceinline__ void wait_acq(int* p, int target) {
    if (threadIdx.x == 0)
        while (__hip_atomic_load(p, __ATOMIC_RELAXED, __HIP_MEMORY_SCOPE_AGENT) < target)
            __builtin_amdgcn_s_sleep(16);
    __syncthreads();
    __builtin_amdgcn_fence(__ATOMIC_ACQUIRE, "agent");
}

// ---- fused normalize_adj + sparse row gather ------------------------------
struct AmulSM {
    float vv[256];
    int   jj[256];
    float part[4];
    int   wcnt[4];
    int   woff[4];
    float sinv;
    int   n0;
};

__device__ __forceinline__ void amul_body(const float* __restrict__ adj,
                                          const float* __restrict__ H,
                                          uint16_t* __restrict__ outp,
                                          int b, int i, int tid, AmulSM* sm)
{
    const float* A = adj + ((size_t)b << 16);
    float aij = A[(i << 8) + tid];
    float aji = A[(tid << 8) + i];
    float v = fmaxf(aij, aji);
    if (tid == i) v += 1.0f;

    float s = v;
    #pragma unroll
    for (int off = 32; off > 0; off >>= 1) s += __shfl_down(s, off);

    bool pred = v != 0.0f;
    unsigned long long m = __ballot(pred);
    int wid = tid >> 6;
    if ((tid & 63) == 0) { sm->part[wid] = s; sm->wcnt[wid] = (int)__popcll(m); }
    __syncthreads();
    if (tid == 0) {
        float t = sm->part[0] + sm->part[1] + sm->part[2] + sm->part[3];
        sm->sinv = t > 0.0f ? 1.0f / t : 0.0f;
        int o = 0;
        #pragma unroll
        for (int w = 0; w < 4; ++w) { sm->woff[w] = o; o += sm->wcnt[w]; }
        sm->n0 = o;
    }
    __syncthreads();
    if (pred) {
        int pos = sm->woff[wid] + (int)__popcll(m & ((1ull << (tid & 63)) - 1ull));
        sm->vv[pos] = v * sm->sinv;
        sm->jj[pos] = tid;
    }
    __syncthreads();

    const int n0 = sm->n0;
    const int f0 = tid * 8;
    const float* Hb = H + (((size_t)b) << 8) * 2048;
    float acc[8] = {};
    for (int c = 0; c < n0; ++c) {
        float av = sm->vv[c];
        const float* hp = Hb + (size_t)sm->jj[c] * 2048 + f0;
        float4 p = *(const float4*)hp;
        float4 q = *(const float4*)(hp + 4);
        acc[0] += av * p.x; acc[1] += av * p.y; acc[2] += av * p.z; acc[3] += av * p.w;
        acc[4] += av * q.x; acc[5] += av * q.y; acc[6] += av * q.z; acc[7] += av * q.w;
    }
    uint4 o;
    o.x = f2bf2(acc[0], acc[1]);
    o.y = f2bf2(acc[2], acc[3]);
    o.z = f2bf2(acc[4], acc[5]);
    o.w = f2bf2(acc[6], acc[7]);
    *(uint4*)(outp + (((size_t)b << 8) + i) * 2048 + f0) = o;
}

// XCD-swizzled (b,i); consecutive ids (2t, 2t+1) share the same b
__device__ __forceinline__ void amul_swizzle(int id, int& b, int& i) {
    int x = id & 7, g = id >> 3;
    b = x >> 1;
    i = ((x & 1) << 7) + g;
}

// ---- dispatch 1: amul#1 | wT | W1/W2-transpose | pad_x (inputs only) ------
#define PR_AM 1024
#define PR_W  3072
#define PR_T  5120
#define PR_N  17456

__global__ __launch_bounds__(256)
void k_prep(const float* __restrict__ x, uint16_t* __restrict__ xpad,
            const float* __restrict__ w, uint16_t* __restrict__ wT,
            const float* __restrict__ W1, const float* __restrict__ W2,
            uint16_t* __restrict__ W1T, uint16_t* __restrict__ W2T,
            const float* __restrict__ adj, const float* __restrict__ nodes,
            uint16_t* __restrict__ gbf)
{
    __shared__ union {
        float  wbuf[6144];
        float  tile[64][65];
        AmulSM am;
    } sm;
    const int bid = blockIdx.x;
    const int tid = threadIdx.x;

    if (bid < PR_AM) {
        int b, i; amul_swizzle(bid, b, i);
        amul_body(adj, nodes, gbf, b, i, tid, &sm.am);
    } else if (bid < PR_W) {
        // conv_w [o][i][h] -> wT [o][h*2048+i] bf16 (LDS-staged)
        int o = bid - PR_AM;
        const float* src = w + (size_t)o * 6144;
        uint16_t*    dst = wT + (size_t)o * 6144;
        #pragma unroll
        for (int it = 0; it < 24; ++it)
            sm.wbuf[it * 256 + tid] = src[it * 256 + tid];
        __syncthreads();
        #pragma unroll
        for (int h = 0; h < 3; ++h)
            #pragma unroll
            for (int c = 0; c < 8; ++c) {
                int i = c * 256 + tid;
                dst[h * 2048 + i] = f2bf(sm.wbuf[i * 3 + h]);   // stride-3: conflict-free
            }
    } else if (bid < PR_T) {
        // W1/W2 [2048][2048] -> bf16 transpose
        int t  = bid - PR_W;
        int z  = t >> 10;
        int by = (t >> 5) & 31;
        int bx = t & 31;
        const float* src = z ? W2 : W1;
        uint16_t*    dst = z ? W2T : W1T;
        int tx = tid & 63, ty = tid >> 6;
        for (int rr = ty; rr < 64; rr += 4)
            sm.tile[rr][tx] = src[(size_t)(by * 64 + rr) * 2048 + bx * 64 + tx];
        __syncthreads();
        for (int rr = ty; rr < 64; rr += 4)
            dst[(size_t)(bx * 64 + rr) * 2048 + by * 64 + tx] = f2bf(sm.tile[tx][rr]);
    } else {
        // x [12,512,2048] f32 -> xpad [12,514,2048] bf16, 4 elems/thread
        int idx4 = (bid - PR_T) * 256 + tid;       // < 3,158,016
        int ch4  = idx4 & 511;
        int tmp  = idx4 >> 9;                      // b*514 + tt
        int b    = tmp / 514;
        int tt   = tmp - b * 514;
        float4 v = {0.0f, 0.0f, 0.0f, 0.0f};
        if (tt >= 1 && tt <= 512)
            v = *(const float4*)(x + ((size_t)(b * 512 + tt - 1) << 11) + ch4 * 4);
        uint2 o = { f2bf2(v.x, v.y), f2bf2(v.z, v.w) };
        ((uint2*)xpad)[idx4] = o;
    }
}

// ---- 64x64 GEMM tile body, BK=64, LDS split-half layout [s][64][32] -------
template<bool RELU>
__device__ __forceinline__ void g64_tile(uint16_t* As, uint16_t* Bs,
                                         const uint16_t* __restrict__ A,
                                         const uint16_t* __restrict__ BT,
                                         float* __restrict__ C, const float* __restrict__ bias,
                                         int rt, int ct)
{
    const int tid  = threadIdx.x;
    const int lane = tid & 63;
    const int wave = tid >> 6;
    const int wm   = (wave >> 1) * 32;
    const int wn   = (wave & 1) * 32;
    const int lm   = lane & 15;
    const int kq   = (lane >> 4) * 8;
    const int sr   = tid >> 2;
    const int sc   = (tid & 3) * 8;

    const size_t abase = (size_t)(rt + sr) * 2048 + sc;
    const size_t bbase = (size_t)(ct + sr) * 2048 + sc;

    floatx4 acc[2][2] = {};

    for (int k0 = 0; k0 < 2048; k0 += 64) {
        #pragma unroll
        for (int p = 0; p < 2; ++p) {
            gload_lds16(A  + abase + k0 + p * 32, &As[p * 2048 + tid * 8]);
            gload_lds16(BT + bbase + k0 + p * 32, &Bs[p * 2048 + tid * 8]);
        }
        __syncthreads();

        #pragma unroll
        for (int s = 0; s < 2; ++s) {
            bf16x8 af[2], bfr[2];
            #pragma unroll
            for (int mt = 0; mt < 2; ++mt)
                af[mt] = *(const bf16x8*)&As[s * 2048 + (wm + mt * 16 + lm) * 32 + kq];
            #pragma unroll
            for (int nt = 0; nt < 2; ++nt)
                bfr[nt] = *(const bf16x8*)&Bs[s * 2048 + (wn + nt * 16 + lm) * 32 + kq];
            #pragma unroll
            for (int mt = 0; mt < 2; ++mt)
                #pragma unroll
                for (int nt = 0; nt < 2; ++nt)
                    acc[mt][nt] = __builtin_amdgcn_mfma_f32_16x16x32_bf16(af[mt], bfr[nt], acc[mt][nt], 0, 0, 0);
        }
        __syncthreads();
    }

    const int lq = lane >> 4;
    #pragma unroll
    for (int mt = 0; mt < 2; ++mt)
        #pragma unroll
        for (int nt = 0; nt < 2; ++nt) {
            int col = ct + wn + nt * 16 + lm;
            float bv = bias[col];
            #pragma unroll
            for (int r = 0; r < 4; ++r) {
                int row = rt + wm + mt * 16 + lq * 4 + r;
                float v = acc[mt][nt][r] + bv;
                if (RELU) v = fmaxf(v, 0.0f);
                C[(size_t)row * 2048 + col] = v;
            }
        }
}

// ---- dispatch 2: conv GEMM (768 blocks) || full GCN chain (512 blocks) ----
// conv: 128x128, BK=64, XCD-swizzled. GCN blocks: g64#1 -> 2x amul#2 -> g64#2
// via flag continuations; all 1280 blocks co-resident (LDS 32KB -> 5/CU),
// conv never waits -> deadlock-free regardless of dispatch order.
__global__ __launch_bounds__(256)
void k_big(const uint16_t* __restrict__ xpad, const uint16_t* __restrict__ wmT,
           float* __restrict__ feats, const float* __restrict__ conv_b,
           const uint16_t* __restrict__ gbf, const uint16_t* __restrict__ W1T,
           float* __restrict__ h, const float* __restrict__ b1,
           const float* __restrict__ adj, uint16_t* __restrict__ ahb,
           const uint16_t* __restrict__ W2T, float* __restrict__ out2,
           const float* __restrict__ b2, int* __restrict__ cntH,
           int* __restrict__ cnt2)
{
    __shared__ __align__(16) union {
        uint16_t u16[16384];
        AmulSM   am;
    } sm;
    const int bid  = blockIdx.x;
    const int tid  = threadIdx.x;
    const int lane = tid & 63;
    const int wave = tid >> 6;
    const int lm   = lane & 15;
    const int kq   = (lane >> 4) * 8;
    const int lq   = lane >> 4;

    if (bid < 768) {
        // ---------------- conv GEMM 128x128, K=6144, BK=64, XCD-swizzled ---
        uint16_t* As = sm.u16;
        uint16_t* Bs = sm.u16 + 8192;
        const int xc = bid & 7;
        const int g  = bid >> 3;            // 0..95
        const int rt = (12 * (xc >> 1) + (g % 12)) * 128;
        const int ct = (8 * (xc & 1) + (g / 12)) * 128;
        const int wm = (wave >> 1) * 64;
        const int wn = (wave & 1) * 64;

        const int sr = tid >> 2;
        const int sc = (tid & 3) * 8;
        size_t arow[2]; size_t brow[2];
        #pragma unroll
        for (int rh = 0; rh < 2; ++rh) {
            int r = rt + rh * 64 + sr;
            int b = r >> 9;
            int t = r & 511;
            arow[rh] = ((size_t)(b * 514 + t) << 11);
            brow[rh] = (size_t)(ct + rh * 64 + sr) * 6144;
        }

        floatx4 acc[4][4] = {};

        for (int k0 = 0; k0 < 6144; k0 += 64) {
            const int hh = k0 >> 11;
            const int icb = (k0 & 2047) + sc;
            #pragma unroll
            for (int p = 0; p < 4; ++p) {
                const int s  = p >> 1;
                const int rh = p & 1;
                gload_lds16(xpad + arow[rh] + ((size_t)hh << 11) + icb + s * 32,
                            &As[p * 2048 + tid * 8]);
                gload_lds16(wmT + brow[rh] + k0 + sc + s * 32,
                            &Bs[p * 2048 + tid * 8]);
            }
            __syncthreads();

            #pragma unroll
            for (int s = 0; s < 2; ++s) {
                bf16x8 af[4], bfr[4];
                #pragma unroll
                for (int mt = 0; mt < 4; ++mt)
                    af[mt] = *(const bf16x8*)&As[s * 4096 + (wm + mt * 16 + lm) * 32 + kq];
                #pragma unroll
                for (int nt = 0; nt < 4; ++nt)
                    bfr[nt] = *(const bf16x8*)&Bs[s * 4096 + (wn + nt * 16 + lm) * 32 + kq];
                #pragma unroll
                for (int mt = 0; mt < 4; ++mt)
                    #pragma unroll
                    for (int nt = 0; nt < 4; ++nt)
                        acc[mt][nt] = __builtin_amdgcn_mfma_f32_16x16x32_bf16(af[mt], bfr[nt], acc[mt][nt], 0, 0, 0);
            }
            __syncthreads();
        }

        #pragma unroll
        for (int mt = 0; mt < 4; ++mt)
            #pragma unroll
            for (int nt = 0; nt < 4; ++nt) {
                int col = ct + wn + nt * 16 + lm;
                float bv = conv_b[col];
                #pragma unroll
                for (int r = 0; r < 4; ++r) {
                    int row = rt + wm + mt * 16 + lq * 4 + r;
                    feats[(size_t)row * 2048 + col] = fmaxf(acc[mt][nt][r] + bv, 0.0f);
                }
            }
    } else {
        // ---------------- GCN chain block ----------------------------------
        const int t  = bid - 768;           // 0..511
        const int xc = t & 7;
        const int g  = t >> 3;              // 0..63
        const int rt = (g & 15) * 64;
        const int ct = (4 * xc + (g >> 4)) * 64;

        // stage 1: h-tile = relu(gbf @ W1T^T + b1)
        g64_tile<true>(sm.u16, sm.u16 + 4096, gbf, W1T, h, b1, rt, ct);
        bump(&cntH[(g & 15) >> 2]);         // batch = rt>>8; 128 tiles/batch

        // stage 2: two amul rows (same batch b by construction)
        int b0, i0, b1i, i1;
        amul_swizzle(2 * t,     b0,  i0);
        amul_swizzle(2 * t + 1, b1i, i1);
        wait_acq(&cntH[b0], 128);           // all h rows of batch b0 ready
        amul_body(adj, h, ahb, b0, i0, tid, &sm.am);
        bump(&cnt2[b0 * 4 + (i0 >> 6)]);
        amul_body(adj, h, ahb, b1i, i1, tid, &sm.am);
        bump(&cnt2[b1i * 4 + (i1 >> 6)]);

        // stage 3: out2-tile = ahb @ W2T^T + b2 (needs ahb rows [rt, rt+64))
        wait_acq(&cnt2[g & 15], 64);
        g64_tile<false>(sm.u16, sm.u16 + 4096, ahb, W2T, out2, b2, rt, ct);
    }
}

// ---- launch ---------------------------------------------------------------

extern "C" void kernel_launch(void* const* d_in, const int* in_sizes, int n_in,
                              void* d_out, int out_size, void* d_ws, size_t ws_size,
                              hipStream_t stream)
{
    const float* x      = (const float*)d_in[0];
    const float* nodes  = (const float*)d_in[1];
    const float* adj    = (const float*)d_in[2];
    const float* conv_w = (const float*)d_in[3];
    const float* conv_b = (const float*)d_in[4];
    const float* W1     = (const float*)d_in[5];
    const float* b1     = (const float*)d_in[6];
    const float* W2     = (const float*)d_in[7];
    const float* b2     = (const float*)d_in[8];
    float* out = (float*)d_out;

    char* ws = (char*)d_ws;
    uint16_t* xpad   = (uint16_t*)(ws);                 // 25,288,704
    uint16_t* wmT    = (uint16_t*)(ws + 25288704);      // 25,165,824
    uint16_t* W1T    = (uint16_t*)(ws + 50454528);      // 8,388,608
    uint16_t* W2T    = (uint16_t*)(ws + 58843136);      // 8,388,608
    uint16_t* gbf    = (uint16_t*)(ws + 67231744);      // 4,194,304  a@nodes (bf16)
    float*    h      = (float*)   (ws + 71426048);      // 8,388,608  relu(gbf@W1+b1)
    uint16_t* ahb    = (uint16_t*)(ws + 79814656);      // 4,194,304  a@h (bf16)
    int*      cnt    = (int*)     (ws + 84008960);      // cntH[4] + cnt2[16]

    hipMemsetAsync(cnt, 0, 128, stream);
    // d1: everything that depends only on inputs
    k_prep<<<PR_N, 256, 0, stream>>>(x, xpad, conv_w, wmT,
                                     W1, W2, W1T, W2T, adj, nodes, gbf);
    // d2: conv GEMM || complete GCN chain (flag-ordered continuations)
    k_big<<<1280, 256, 0, stream>>>(xpad, wmT, out, conv_b, gbf, W1T, h, b1,
                                    adj, ahb, W2T, out + 12582912, b2,
                                    cnt, cnt + 4);
}